// Round 5
// baseline (120.613 us; speedup 1.0000x reference)
//
#include <hip/hip_runtime.h>
#include <hip/hip_bf16.h>

// scores[b,t] = sum_u tanh((source@W1)[b,u] + (target@W2)[b,t,u]) * a[u]
// B=64 T=8192 D=256 U=128. Memory-bound: 537MB target read at ~6.3TB/s => ~86us floor.
// Round 5: per-wave k-quarter phase skew. R4 stalled at 5.0TB/s (79%) with all pipes
// idle; theory: all waves advance k-quarters in lockstep so concurrent loads share
// address bits [9:8] (q*256B) -> 3/4 of HBM channels idle per phase. Wave w now
// reads quarters (j+w)&3 (k-sum commutative), spreading the instantaneous footprint
// over all four 256B column phases. Otherwise identical to round 4.

#define B_ 64
#define T_ 8192
#define D_ 256
#define U_ 128
#define LDSW 264   // bf16 elems/row; 528B rows -> b128 frag reads hit the 8-cyc floor

typedef __attribute__((ext_vector_type(8))) short bf16x8;
typedef __attribute__((ext_vector_type(4))) float f32x4;

__device__ __forceinline__ short f2bf(float f) {
    unsigned u = __builtin_bit_cast(unsigned, f);
    u += 0x7fffu + ((u >> 16) & 1u);   // RTNE
    return (short)(u >> 16);
}

__device__ __forceinline__ float fast_tanh(float x) {
    float e = __expf(2.0f * x);        // v_exp_f32 path
    return 1.0f - 2.0f * __builtin_amdgcn_rcpf(e + 1.0f);
}

__device__ __forceinline__ bf16x8 cvt8(const float4& a, const float4& b) {
    union { __hip_bfloat162 h[4]; bf16x8 v; } u;
    u.h[0] = __float22bfloat162_rn(make_float2(a.x, a.y));
    u.h[1] = __float22bfloat162_rn(make_float2(a.z, a.w));
    u.h[2] = __float22bfloat162_rn(make_float2(b.x, b.y));
    u.h[3] = __float22bfloat162_rn(make_float2(b.z, b.w));
    return u.v;
}

__global__ __launch_bounds__(512)
__attribute__((amdgpu_waves_per_eu(4, 4)))
void additive_attn_kernel(
        const float* __restrict__ target,
        const float* __restrict__ source,
        const float* __restrict__ W1,
        const float* __restrict__ W2,
        const float* __restrict__ attn,
        float* __restrict__ out) {
    __shared__ __attribute__((aligned(16))) short lds_w2[U_ * LDSW]; // [u][d] bf16
    __shared__ float  lds_red[512];
    __shared__ float2 lds_sa[U_];   // {s_u, a_u}

    const int tid = threadIdx.x;
    const int bx  = blockIdx.x;
    const int b   = bx >> 3;            // 8 blocks per batch element
    const int tb  = (bx & 7) << 10;     // 1024 rows per block

    const int lane = tid & 63;
    const int wave = tid >> 6;   // 0..7
    const int c = lane & 15;
    const int g = lane >> 4;

    const float* tgt  = target + ((size_t)b * T_ + tb) * D_;
    float*       outp = out + (size_t)b * T_ + tb;
    const float* Abase = tgt + (size_t)(wave * 16 + c) * D_ + g * 8;

    // 3 payload sets (4 x float4 each): 48 VGPRs
    float4 p0, p1, p2, p3, q0, q1, q2, q3, r0, r1, r2, r3;

    // k-quarter phase skew: wave w does quarter ((bi + w) & 3) of row-tile bi>>2.
#define QOF(BI) ((((BI) + wave) & 3) * 64)
#define LOADB(X0, X1, X2, X3, BI) do {                                        \
    const float* p_ = Abase + (size_t)((BI) >> 2) * (128 * D_) + QOF(BI);     \
    X0 = *(const float4*)(p_);      X1 = *(const float4*)(p_ + 4);            \
    X2 = *(const float4*)(p_ + 32); X3 = *(const float4*)(p_ + 36);           \
} while (0)

    // prime 2 batches before the prologue (8KB/wave in flight over staging)
    LOADB(p0, p1, p2, p3, 0);
    LOADB(q0, q1, q2, q3, 1);

    // --- stage W2: fp32 [D][U] -> bf16 LDS [u][d], b128 writes ---
    {
        const int u    = tid & (U_ - 1);
        const int dblk = (tid >> 7) << 6;    // 0,64,128,192
        #pragma unroll
        for (int w = 0; w < 8; ++w) {
            const int d0 = dblk + w * 8;
            bf16x8 v;
            #pragma unroll
            for (int i = 0; i < 8; ++i)
                v[i] = f2bf(W2[(size_t)(d0 + i) * U_ + u]);
            *(bf16x8*)&lds_w2[u * LDSW + d0] = v;
        }
    }

    // --- s[u] = (source[b] @ W1)[u], 4-way D split ---
    {
        const float* src = source + b * D_;
        const int u    = tid & (U_ - 1);
        const int part = tid >> 7;
        float acc = 0.f;
        #pragma unroll 8
        for (int d = part * 64; d < part * 64 + 64; ++d)
            acc = fmaf(src[d], W1[(size_t)d * U_ + u], acc);
        lds_red[tid] = acc;
    }
    __syncthreads();
    if (tid < U_)
        lds_sa[tid] = make_float2(
            lds_red[tid] + lds_red[tid + 128] + lds_red[tid + 256] + lds_red[tid + 384],
            attn[tid]);
    __syncthreads();

    f32x4 acc[8];
    #pragma unroll
    for (int j = 0; j < 8; ++j) acc[j] = (f32x4){0.f, 0.f, 0.f, 0.f};

    // swapped operands: A-op = W2 frag (m = u-in-tile), B-op = target (n = row c).
    // LDS k-base must match the wave's phased quarter.
#define COMP(X0, X1, X2, X3, BI) do {                                         \
    bf16x8 af0 = cvt8(X0, X1);                                                \
    bf16x8 af1 = cvt8(X2, X3);                                                \
    const int kb_ = QOF(BI) + g * 8;                                          \
    _Pragma("unroll")                                                         \
    for (int j = 0; j < 8; ++j) {                                             \
        bf16x8 w0 = *(const bf16x8*)&lds_w2[(16 * j + c) * LDSW + kb_];       \
        acc[j] = __builtin_amdgcn_mfma_f32_16x16x32_bf16(w0, af0, acc[j], 0, 0, 0); \
        bf16x8 w1 = *(const bf16x8*)&lds_w2[(16 * j + c) * LDSW + kb_ + 32];  \
        acc[j] = __builtin_amdgcn_mfma_f32_16x16x32_bf16(w1, af1, acc[j], 0, 0, 0); \
    }                                                                         \
} while (0)

    // lane (c,g) holds t[row][u=16j+4g+r] in acc[j][r]; row = rt*128+wave*16+c
#define EPI(IT) do {                                                          \
    float sc = 0.f;                                                           \
    _Pragma("unroll")                                                         \
    for (int j = 0; j < 8; ++j) {                                             \
        float4 sa01 = *(const float4*)&lds_sa[16 * j + 4 * g];                \
        float4 sa23 = *(const float4*)&lds_sa[16 * j + 4 * g + 2];            \
        sc += fast_tanh(acc[j][0] + sa01.x) * sa01.y;                         \
        sc += fast_tanh(acc[j][1] + sa01.z) * sa01.w;                         \
        sc += fast_tanh(acc[j][2] + sa23.x) * sa23.y;                         \
        sc += fast_tanh(acc[j][3] + sa23.z) * sa23.w;                         \
        acc[j] = (f32x4){0.f, 0.f, 0.f, 0.f};                                 \
    }                                                                         \
    sc += __shfl_xor(sc, 16);                                                 \
    sc += __shfl_xor(sc, 32);                                                 \
    if (lane < 16) outp[(IT) * 128 + wave * 16 + lane] = sc;                  \
} while (0)

    // 32 batches = 8 row-tiles x 4 k-quarters (per-wave phased); 3-deep pipeline.
    #pragma unroll
    for (int bi = 0; bi < 32; ++bi) {
        if (bi % 3 == 0) {
            if (bi < 30) LOADB(r0, r1, r2, r3, bi + 2);
            COMP(p0, p1, p2, p3, bi);
        } else if (bi % 3 == 1) {
            if (bi < 30) LOADB(p0, p1, p2, p3, bi + 2);
            COMP(q0, q1, q2, q3, bi);
        } else {
            if (bi < 30) LOADB(q0, q1, q2, q3, bi + 2);
            COMP(r0, r1, r2, r3, bi);
        }
        if ((bi & 3) == 3) EPI(bi >> 2);
    }

#undef LOADB
#undef COMP
#undef EPI
#undef QOF
}

extern "C" void kernel_launch(void* const* d_in, const int* in_sizes, int n_in,
                              void* d_out, int out_size, void* d_ws, size_t ws_size,
                              hipStream_t stream) {
    const float* target = (const float*)d_in[0];
    const float* source = (const float*)d_in[1];
    const float* W1     = (const float*)d_in[2];
    const float* W2     = (const float*)d_in[3];
    const float* attn   = (const float*)d_in[4];
    float* out = (float*)d_out;

    dim3 grid(B_ * (T_ / 1024));   // 512 blocks = 2 per CU, one dispatch round
    dim3 block(512);
    hipLaunchKernelGGL(additive_attn_kernel, grid, block, 0, stream,
                       target, source, W1, W2, attn, out);
}